// Round 2
// baseline (3318.214 us; speedup 1.0000x reference)
//
#include <hip/hip_runtime.h>
#include <math.h>

// LSTM persistent kernel: one block per batch element, 512 threads.
// Thread (base=tid>>2, q=tid&3) owns gate rows base+{0,128,256,384},
// k-chunk [32q, 32q+32). Quad DPP allreduce -> lane-local c/h update.
//
// R2 change: amdgpu_waves_per_eu(2,2) pins occupancy at exactly 2 waves/EU
// (256 VGPR/wave budget) so the 128-float weight array + 32-float h fragment
// stay in arch VGPRs. R1 showed VGPR_Count=84 -> compiler targeted 4 waves/EU
// and shoved weights into AGPR/scratch (~+1000 cy/step of accvgpr/reload ops).
constexpr int Hdim = 128;
constexpr int TMAX = 4096;

template <int CTRL>
__device__ __forceinline__ float quad_swap(float v) {
  int r = __builtin_amdgcn_update_dpp(0, __float_as_int(v), CTRL, 0xF, 0xF, true);
  return __int_as_float(r);
}

__device__ __forceinline__ float fast_sigmoid(float x) {
  return 1.0f / (1.0f + __expf(-x));
}
__device__ __forceinline__ float fast_tanh(float x) {
  // tanh(x) = 1 - 2/(exp(2x)+1); saturates correctly via inf handling
  return 1.0f - 2.0f / (__expf(2.0f * x) + 1.0f);
}

__global__ __launch_bounds__(512)
__attribute__((amdgpu_waves_per_eu(2, 2))) void lstm_persist(
    const float* __restrict__ data, const float* __restrict__ h0,
    const float* __restrict__ c0, const float* __restrict__ W_ih,
    const float* __restrict__ W_hh, const float* __restrict__ b_ih,
    const float* __restrict__ b_hh, const float* __restrict__ W_out,
    const float* __restrict__ b_out, float* __restrict__ out, int T) {
  __shared__ __align__(16) float xs[TMAX];
  // ping-pong x 4 replicas x 132-float stagger (conflict-free quad reads)
  __shared__ __align__(16) float hrep[2][4][132];

  const int b = blockIdx.x;
  const int tid = threadIdx.x;
  const int q = tid & 3;
  const int base = tid >> 2;

  // Stage this batch's input row into LDS (vectorized, coalesced).
  {
    const float4* src = (const float4*)(data + (size_t)b * T);
    float4* dst = (float4*)xs;
    for (int i = tid; i < T / 4; i += 512) dst[i] = src[i];
  }

  // Load recurrent weights into registers: 4 rows x 32 k-elems = 128 VGPRs.
  float w[4][32];
#pragma unroll
  for (int r = 0; r < 4; ++r) {
    const float* wr = W_hh + (size_t)(base + 128 * r) * Hdim + 32 * q;
#pragma unroll
    for (int j = 0; j < 8; ++j) {
      float4 v = ((const float4*)wr)[j];
      w[r][4 * j + 0] = v.x;
      w[r][4 * j + 1] = v.y;
      w[r][4 * j + 2] = v.z;
      w[r][4 * j + 3] = v.w;
    }
  }
  float wih[4], bsum[4];
#pragma unroll
  for (int r = 0; r < 4; ++r) {
    const int row = base + 128 * r;
    wih[r] = W_ih[row];
    bsum[r] = b_ih[row] + b_hh[row];
  }

  float c = c0[(size_t)b * Hdim + base];
  if (q == 0) {
    const float h = h0[(size_t)b * Hdim + base];
    hrep[0][0][base] = h;
    hrep[0][1][base] = h;
    hrep[0][2][base] = h;
    hrep[0][3][base] = h;
  }
  __syncthreads();

  for (int t = 0; t < T; ++t) {
    // Read my 32-float chunk of h from my staggered replica (ds_read_b128 x8).
    const float4* hp = (const float4*)(&hrep[t & 1][q][32 * q]);
    float4 hv[8];
#pragma unroll
    for (int j = 0; j < 8; ++j) hv[j] = hp[j];

    float s0 = 0.f, s1 = 0.f, s2 = 0.f, s3 = 0.f;
#pragma unroll
    for (int j = 0; j < 8; ++j) {
      s0 = fmaf(w[0][4 * j + 0], hv[j].x, s0);
      s0 = fmaf(w[0][4 * j + 1], hv[j].y, s0);
      s0 = fmaf(w[0][4 * j + 2], hv[j].z, s0);
      s0 = fmaf(w[0][4 * j + 3], hv[j].w, s0);
      s1 = fmaf(w[1][4 * j + 0], hv[j].x, s1);
      s1 = fmaf(w[1][4 * j + 1], hv[j].y, s1);
      s1 = fmaf(w[1][4 * j + 2], hv[j].z, s1);
      s1 = fmaf(w[1][4 * j + 3], hv[j].w, s1);
      s2 = fmaf(w[2][4 * j + 0], hv[j].x, s2);
      s2 = fmaf(w[2][4 * j + 1], hv[j].y, s2);
      s2 = fmaf(w[2][4 * j + 2], hv[j].z, s2);
      s2 = fmaf(w[2][4 * j + 3], hv[j].w, s2);
      s3 = fmaf(w[3][4 * j + 0], hv[j].x, s3);
      s3 = fmaf(w[3][4 * j + 1], hv[j].y, s3);
      s3 = fmaf(w[3][4 * j + 2], hv[j].z, s3);
      s3 = fmaf(w[3][4 * j + 3], hv[j].w, s3);
    }

    // Quad allreduce (DPP quad_perm, stays in VALU pipe). All 4 lanes of the
    // quad end with bitwise-identical full dot products for element `base`.
    s0 += quad_swap<0xB1>(s0);
    s0 += quad_swap<0x4E>(s0);
    s1 += quad_swap<0xB1>(s1);
    s1 += quad_swap<0x4E>(s1);
    s2 += quad_swap<0xB1>(s2);
    s2 += quad_swap<0x4E>(s2);
    s3 += quad_swap<0xB1>(s3);
    s3 += quad_swap<0x4E>(s3);

    const float xt = xs[t];
    const float ig = fast_sigmoid(fmaf(xt, wih[0], bsum[0]) + s0);
    const float fg = fast_sigmoid(fmaf(xt, wih[1], bsum[1]) + s1);
    const float gg = fast_tanh(fmaf(xt, wih[2], bsum[2]) + s2);
    const float og = fast_sigmoid(fmaf(xt, wih[3], bsum[3]) + s3);
    c = fmaf(fg, c, ig * gg);
    const float h = og * fast_tanh(c);

    if (q == 0) {
      float* hn = &hrep[(t + 1) & 1][0][0];
      hn[0 * 132 + base] = h;
      hn[1 * 132 + base] = h;
      hn[2 * 132 + base] = h;
      hn[3 * 132 + base] = h;
    }
    __syncthreads();
  }

  // Final linear: out[b] = h_T . W_out + b_out (wave 0 only).
  if (tid < 64) {
    const float* hf = &hrep[T & 1][0][0];
    float sum = hf[tid] * W_out[tid] + hf[tid + 64] * W_out[tid + 64];
#pragma unroll
    for (int off = 32; off > 0; off >>= 1) sum += __shfl_down(sum, off, 64);
    if (tid == 0) out[b] = sum + b_out[0];
  }
}

extern "C" void kernel_launch(void* const* d_in, const int* in_sizes, int n_in,
                              void* d_out, int out_size, void* d_ws,
                              size_t ws_size, hipStream_t stream) {
  const float* data = (const float*)d_in[0];
  const float* h0 = (const float*)d_in[1];
  const float* c0 = (const float*)d_in[2];
  const float* W_ih = (const float*)d_in[3];
  const float* W_hh = (const float*)d_in[4];
  const float* b_ih = (const float*)d_in[5];
  const float* b_hh = (const float*)d_in[6];
  const float* W_out = (const float*)d_in[7];
  const float* b_out = (const float*)d_in[8];
  float* out = (float*)d_out;

  const int B = in_sizes[1] / Hdim;  // 64
  const int T = in_sizes[0] / B;     // 4096

  lstm_persist<<<B, 512, 0, stream>>>(data, h0, c0, W_ih, W_hh, b_ih, b_hh,
                                      W_out, b_out, out, T);
}

// Round 3
// 2610.222 us; speedup vs baseline: 1.2712x; 1.2712x over previous
//
#include <hip/hip_runtime.h>
#include <math.h>

// LSTM persistent kernel, R3: one block per batch element, 1024 threads.
// Oct (8 lanes) owns one h-element e=tid>>3; lane o=tid&7 holds gate rows
// e+{0,128,256,384} restricted to k-chunk [16o,16o+16) -> 64 weight VGPRs
// per thread (fits a 128-reg budget; defeats the AGPR-spill junk seen in
// R1/R2 where 128 weights/thread forced VGPR_Count=88 + AGPR round-trips).
// Oct allreduce = 3 DPP stages; activations gate-specialized per lane
// (g=o&3) then quad_perm-broadcast back; rcp/exp native (no IEEE div).
constexpr int Hdim = 128;
constexpr int TMAX = 4096;
constexpr int REP = 132;  // replica stride (floats): staggered, conflict-free

template <int CTRL>
__device__ __forceinline__ float dppf(float v) {
  return __int_as_float(
      __builtin_amdgcn_update_dpp(0, __float_as_int(v), CTRL, 0xF, 0xF, true));
}

__global__ __launch_bounds__(1024) void lstm_persist(
    const float* __restrict__ data, const float* __restrict__ h0,
    const float* __restrict__ c0, const float* __restrict__ W_ih,
    const float* __restrict__ W_hh, const float* __restrict__ b_ih,
    const float* __restrict__ b_hh, const float* __restrict__ W_out,
    const float* __restrict__ b_out, float* __restrict__ out, int T) {
  __shared__ __align__(16) float xs[TMAX];
  // ping-pong x 8 replicas x REP-float stagger; lane o reads replica o at
  // dword offset 148*o -> bank groups {0,20,8,28,16,4,24,12}+[0..3]: all 32
  // banks exactly once per ds_read_b128 issue, same-addr across e = broadcast.
  __shared__ __align__(16) float hrep[2][8 * REP];

  const int b = blockIdx.x;
  const int tid = threadIdx.x;
  const int o = tid & 7;
  const int e = tid >> 3;
  const int g = o & 3;

  // Stage this batch's input row into LDS (coalesced float4).
  {
    const float4* src = (const float4*)(data + (size_t)b * T);
    float4* dst = (float4*)xs;
    for (int i = tid; i < T / 4; i += 1024) dst[i] = src[i];
  }

  // Weights: 4 rows x 16 k-elems = 64 VGPRs.
  float w[4][16];
#pragma unroll
  for (int r = 0; r < 4; ++r) {
    const float* wr = W_hh + (size_t)(e + 128 * r) * Hdim + 16 * o;
#pragma unroll
    for (int j = 0; j < 4; ++j) {
      float4 v = ((const float4*)wr)[j];
      w[r][4 * j + 0] = v.x;
      w[r][4 * j + 1] = v.y;
      w[r][4 * j + 2] = v.z;
      w[r][4 * j + 3] = v.w;
    }
  }

  // Lane-constant activation parameters for MY gate (g: 0=i,1=f,2=g,3=o).
  // sigmoid(x) = rcp(1+exp(-x)) ; tanh(x) = 1 - 2*rcp(1+exp(2x))
  const int row = e + 128 * g;
  const float wihL = W_ih[row];
  const float bsL = b_ih[row] + b_hh[row];
  const float Ms = (g == 2) ? 2.0f : -1.0f;
  const float As = (g == 2) ? -2.0f : 1.0f;
  const float Bs = (g == 2) ? 1.0f : 0.0f;
  const bool b0 = (g & 1) != 0;
  const bool b1 = (g & 2) != 0;

  float c = c0[(size_t)b * Hdim + e];
  hrep[0][o * REP + e] = h0[(size_t)b * Hdim + e];
  __syncthreads();

  for (int t = 0; t < T; ++t) {
    // My 16-float chunk of h from my staggered replica (4x ds_read_b128).
    const float4* hp = (const float4*)(&hrep[t & 1][o * REP + 16 * o]);
    float4 hv[4];
#pragma unroll
    for (int j = 0; j < 4; ++j) hv[j] = hp[j];

    float s0 = 0.f, s1 = 0.f, s2 = 0.f, s3 = 0.f;
#pragma unroll
    for (int j = 0; j < 4; ++j) {
      s0 = fmaf(w[0][4 * j + 0], hv[j].x, s0);
      s0 = fmaf(w[0][4 * j + 1], hv[j].y, s0);
      s0 = fmaf(w[0][4 * j + 2], hv[j].z, s0);
      s0 = fmaf(w[0][4 * j + 3], hv[j].w, s0);
      s1 = fmaf(w[1][4 * j + 0], hv[j].x, s1);
      s1 = fmaf(w[1][4 * j + 1], hv[j].y, s1);
      s1 = fmaf(w[1][4 * j + 2], hv[j].z, s1);
      s1 = fmaf(w[1][4 * j + 3], hv[j].w, s1);
      s2 = fmaf(w[2][4 * j + 0], hv[j].x, s2);
      s2 = fmaf(w[2][4 * j + 1], hv[j].y, s2);
      s2 = fmaf(w[2][4 * j + 2], hv[j].z, s2);
      s2 = fmaf(w[2][4 * j + 3], hv[j].w, s2);
      s3 = fmaf(w[3][4 * j + 0], hv[j].x, s3);
      s3 = fmaf(w[3][4 * j + 1], hv[j].y, s3);
      s3 = fmaf(w[3][4 * j + 2], hv[j].z, s3);
      s3 = fmaf(w[3][4 * j + 3], hv[j].w, s3);
    }

    // Oct allreduce: xor1 (quad_perm), xor2 (quad_perm), xor7 (half-mirror).
    s0 += dppf<0xB1>(s0);
    s0 += dppf<0x4E>(s0);
    s0 += dppf<0x141>(s0);
    s1 += dppf<0xB1>(s1);
    s1 += dppf<0x4E>(s1);
    s1 += dppf<0x141>(s1);
    s2 += dppf<0xB1>(s2);
    s2 += dppf<0x4E>(s2);
    s2 += dppf<0x141>(s2);
    s3 += dppf<0xB1>(s3);
    s3 += dppf<0x4E>(s3);
    s3 += dppf<0x141>(s3);

    // Lane computes activation for its own gate only.
    const float sg = b1 ? (b0 ? s3 : s2) : (b0 ? s1 : s0);
    const float pre = fmaf(xs[t], wihL, bsL) + sg;
    const float y =
        fmaf(As, __builtin_amdgcn_rcpf(1.0f + __expf(Ms * pre)), Bs);

    // Quad broadcast: lanes (4q..4q+3) hold gates i,f,g,o in order.
    const float yi = dppf<0x00>(y);
    const float yf = dppf<0x55>(y);
    const float yg = dppf<0xAA>(y);
    const float yo = dppf<0xFF>(y);

    c = fmaf(yf, c, yi * yg);
    const float th =
        fmaf(-2.0f, __builtin_amdgcn_rcpf(1.0f + __expf(2.0f * c)), 1.0f);
    const float h = yo * th;

    hrep[(t + 1) & 1][o * REP + e] = h;  // lane o fills replica o (2-way, free)
    __syncthreads();
  }

  // Final linear: out[b] = h_T . W_out + b_out (wave 0, replica 0).
  if (tid < 64) {
    const float* hf = &hrep[T & 1][0];
    float sum = hf[tid] * W_out[tid] + hf[tid + 64] * W_out[tid + 64];
#pragma unroll
    for (int off = 32; off > 0; off >>= 1) sum += __shfl_down(sum, off, 64);
    if (tid == 0) out[b] = sum + b_out[0];
  }
}

extern "C" void kernel_launch(void* const* d_in, const int* in_sizes, int n_in,
                              void* d_out, int out_size, void* d_ws,
                              size_t ws_size, hipStream_t stream) {
  const float* data = (const float*)d_in[0];
  const float* h0 = (const float*)d_in[1];
  const float* c0 = (const float*)d_in[2];
  const float* W_ih = (const float*)d_in[3];
  const float* W_hh = (const float*)d_in[4];
  const float* b_ih = (const float*)d_in[5];
  const float* b_hh = (const float*)d_in[6];
  const float* W_out = (const float*)d_in[7];
  const float* b_out = (const float*)d_in[8];
  float* out = (float*)d_out;

  const int B = in_sizes[1] / Hdim;  // 64
  const int T = in_sizes[0] / B;     // 4096

  lstm_persist<<<B, 1024, 0, stream>>>(data, h0, c0, W_ih, W_hh, b_ih, b_hh,
                                       W_out, b_out, out, T);
}

// Round 4
// 2130.786 us; speedup vs baseline: 1.5573x; 1.2250x over previous
//
#include <hip/hip_runtime.h>
#include <math.h>

// LSTM persistent kernel, R4: one block per batch element, 512 threads.
// Quad (4 lanes) owns h-element e=tid>>2; lane q=tid&3 holds gate rows
// e+{0,128,256,384} restricted to k-chunk [32q,32q+32) -> 128 weight floats
// kept as 64 float2 pairs feeding v_pk_fma_f32 (2 FMA/instr, the only way to
// reach the 157-TF fp32 rate). Per-SIMD overhead scales with thread count
// (O x waves/SIMD), so 512 threads halves the replicated reduce/act/c-chain
// cost vs R3's 1024. Reduce is a 2-stage DPP reduce-scatter (lane ends with
// only ITS gate's full sum), activations are exp2/rcp based (no IEEE div --
// R1's real killer), single ds_write/lane, unroll-2 for static ping-pong.
constexpr int Hdim = 128;
constexpr int TMAX = 4096;
constexpr int REP = 132;  // replica stride: 4 staggered replicas, 0 conflicts (R1-verified)

typedef float v2f __attribute__((ext_vector_type(2)));

template <int CTRL>
__device__ __forceinline__ float dppf(float v) {
  return __int_as_float(
      __builtin_amdgcn_update_dpp(0, __float_as_int(v), CTRL, 0xF, 0xF, true));
}

#if __has_builtin(__builtin_amdgcn_exp2f)
__device__ __forceinline__ float exp2_fast(float x) {
  return __builtin_amdgcn_exp2f(x);
}
#else
__device__ __forceinline__ float exp2_fast(float x) {
  return __expf(x * 0.6931471805599453f);  // exp(x ln2) = 2^x
}
#endif

__global__ __launch_bounds__(512, 2) void lstm_persist(
    const float* __restrict__ data, const float* __restrict__ h0,
    const float* __restrict__ c0, const float* __restrict__ W_ih,
    const float* __restrict__ W_hh, const float* __restrict__ b_ih,
    const float* __restrict__ b_hh, const float* __restrict__ W_out,
    const float* __restrict__ b_out, float* __restrict__ out, int T) {
  __shared__ __align__(16) float xs[TMAX];
  // ping-pong x 4 replicas x REP stagger. Lane q reads replica q chunk
  // [32q,32q+32): dword addr 164q+4j+l -> 16 distinct banks, 0 conflicts.
  __shared__ __align__(16) float hrep[2][4 * REP];

  const int b = blockIdx.x;
  const int tid = threadIdx.x;
  const int q = tid & 3;
  const int e = tid >> 2;

  // Stage input row (coalesced float4).
  {
    const float4* src = (const float4*)(data + (size_t)b * T);
    float4* dst = (float4*)xs;
    for (int i = tid; i < T / 4; i += 512) dst[i] = src[i];
  }

  // Weights: 4 gate rows x 32 k = 64 packed pairs.
  v2f w2[4][16];
#pragma unroll
  for (int r = 0; r < 4; ++r) {
    const float* wr = W_hh + (size_t)(e + 128 * r) * Hdim + 32 * q;
#pragma unroll
    for (int j = 0; j < 8; ++j) {
      float4 v = ((const float4*)wr)[j];
      w2[r][2 * j + 0] = v2f{v.x, v.y};
      w2[r][2 * j + 1] = v2f{v.z, v.w};
    }
  }

  // Lane-constant activation params for MY gate (q: 0=i,1=f,2=g,3=o).
  // sigmoid(p)=rcp(1+2^(-p*log2e)); tanh(p)=1-2*rcp(1+2^(p*2log2e))
  constexpr float L2E = 1.44269504088896f;
  const int row = e + 128 * q;
  const float wihL = W_ih[row];
  const float bsL = b_ih[row] + b_hh[row];
  const float Mk = (q == 2) ? 2.0f * L2E : -L2E;
  const float As = (q == 2) ? -2.0f : 1.0f;
  const float Bs = (q == 2) ? 1.0f : 0.0f;
  const bool qb0 = (q & 1) != 0;
  const bool qb1 = (q & 2) != 0;

  float c = c0[(size_t)b * Hdim + e];
  if (q == 0) {
    const float h = h0[(size_t)b * Hdim + e];
    hrep[0][0 * REP + e] = h;
    hrep[0][1 * REP + e] = h;
    hrep[0][2 * REP + e] = h;
    hrep[0][3 * REP + e] = h;
  }
  __syncthreads();

#pragma unroll 2
  for (int t = 0; t < T; ++t) {
    // My 32-float chunk of h (8x ds_read_b128, conflict-free stagger).
    const float4* hp = (const float4*)(&hrep[t & 1][q * REP + 32 * q]);
    const float xt = xs[t];

    v2f a0 = {0.f, 0.f}, a1 = {0.f, 0.f}, a2 = {0.f, 0.f}, a3 = {0.f, 0.f};
#pragma unroll
    for (int j = 0; j < 8; ++j) {
      const float4 v = hp[j];
      const v2f hA = {v.x, v.y};
      const v2f hB = {v.z, v.w};
      a0 = __builtin_elementwise_fma(w2[0][2 * j + 0], hA, a0);
      a0 = __builtin_elementwise_fma(w2[0][2 * j + 1], hB, a0);
      a1 = __builtin_elementwise_fma(w2[1][2 * j + 0], hA, a1);
      a1 = __builtin_elementwise_fma(w2[1][2 * j + 1], hB, a1);
      a2 = __builtin_elementwise_fma(w2[2][2 * j + 0], hA, a2);
      a2 = __builtin_elementwise_fma(w2[2][2 * j + 1], hB, a2);
      a3 = __builtin_elementwise_fma(w2[3][2 * j + 0], hA, a3);
      a3 = __builtin_elementwise_fma(w2[3][2 * j + 1], hB, a3);
    }
    const float s0 = a0.x + a0.y;
    const float s1 = a1.x + a1.y;
    const float s2 = a2.x + a2.y;
    const float s3 = a3.x + a3.y;

    // 2-stage DPP reduce-scatter: lane q ends with gate q's full 128-k sum.
    // Stage 1 (xor1): pair gates by bit0; send partner its needed partial.
    float x01 = qb0 ? s1 : s0;
    float y01 = qb0 ? s0 : s1;
    x01 += dppf<0xB1>(y01);
    float x23 = qb0 ? s3 : s2;
    float y23 = qb0 ? s2 : s3;
    x23 += dppf<0xB1>(y23);
    // Stage 2 (xor2): select by bit1.
    float z = qb1 ? x23 : x01;
    float zz = qb1 ? x01 : x23;
    z += dppf<0x4E>(zz);

    // Activation for my own gate only.
    const float pre = fmaf(xt, wihL, bsL) + z;
    const float y =
        fmaf(As, __builtin_amdgcn_rcpf(1.0f + exp2_fast(pre * Mk)), Bs);

    // Quad broadcast: gather i,f,g,o into every lane.
    const float yi = dppf<0x00>(y);
    const float yf = dppf<0x55>(y);
    const float yg = dppf<0xAA>(y);
    const float yo = dppf<0xFF>(y);

    c = fmaf(yf, c, yi * yg);
    const float th = fmaf(
        -2.0f, __builtin_amdgcn_rcpf(1.0f + exp2_fast(c * (2.0f * L2E))), 1.0f);
    const float h = yo * th;

    hrep[(t + 1) & 1][q * REP + e] = h;  // lane q fills replica q (~2-way, free)
    __syncthreads();
  }

  // Final linear: out[b] = h_T . W_out + b_out (wave 0, replica 0).
  if (tid < 64) {
    const float* hf = &hrep[T & 1][0];
    float sum = hf[tid] * W_out[tid] + hf[tid + 64] * W_out[tid + 64];
#pragma unroll
    for (int off = 32; off > 0; off >>= 1) sum += __shfl_down(sum, off, 64);
    if (tid == 0) out[b] = sum + b_out[0];
  }
}

extern "C" void kernel_launch(void* const* d_in, const int* in_sizes, int n_in,
                              void* d_out, int out_size, void* d_ws,
                              size_t ws_size, hipStream_t stream) {
  const float* data = (const float*)d_in[0];
  const float* h0 = (const float*)d_in[1];
  const float* c0 = (const float*)d_in[2];
  const float* W_ih = (const float*)d_in[3];
  const float* W_hh = (const float*)d_in[4];
  const float* b_ih = (const float*)d_in[5];
  const float* b_hh = (const float*)d_in[6];
  const float* W_out = (const float*)d_in[7];
  const float* b_out = (const float*)d_in[8];
  float* out = (float*)d_out;

  const int B = in_sizes[1] / Hdim;  // 64
  const int T = in_sizes[0] / B;     // 4096

  lstm_persist<<<B, 512, 0, stream>>>(data, h0, c0, W_ih, W_hh, b_ih, b_hh,
                                      W_out, b_out, out, T);
}

// Round 5
// 1938.169 us; speedup vs baseline: 1.7120x; 1.0994x over previous
//
#include <hip/hip_runtime.h>
#include <math.h>

// LSTM persistent kernel, R5: one block per batch element, 512 threads.
// Quad (4 lanes) owns h-element e=tid>>2; lane q=tid&3 holds gate rows
// e+{0,128,256,384} restricted to k-chunk [32q,32q+32).
//
// R5 change: matvec in f16 via v_dot2_f32_f16 (__builtin_amdgcn_fdot2):
// 2 MACs/lane/instr, fp32 accumulate, FULL VALU rate (2cy/wave64) -- unlike
// v_pk_fma_f32 which is 4cy (157-TF spec pins it; R4's packing saved zero
// FMA cycles). Matvec issue halves 512->256 cy/SIMD/step. Weights f16
// (64 VGPRs), h stored f16 in LDS (4x ds_read_b128/thread). Gate scale
// Mk(r) folded into weights (lane-uniform per gate, commutes with the
// reduce) -> shorter serial exp chain. xs prefetched 4 steps/float4.
constexpr int Hdim = 128;
constexpr int TMAX = 4096;
constexpr int REPH = 136;  // replica stride in halfs: 128+8 pad.
// Read banks: lane q's b128 reads start at byte 2*(136q+32q)=336q -> dword
// 84q -> banks {0,20,8,28}+4j: 16 distinct banks/issue, conflict-free.

typedef _Float16 v2h __attribute__((ext_vector_type(2)));

template <int CTRL>
__device__ __forceinline__ float dppf(float v) {
  return __int_as_float(
      __builtin_amdgcn_update_dpp(0, __float_as_int(v), CTRL, 0xF, 0xF, true));
}

#if __has_builtin(__builtin_amdgcn_exp2f)
__device__ __forceinline__ float exp2_fast(float x) {
  return __builtin_amdgcn_exp2f(x);
}
#else
__device__ __forceinline__ float exp2_fast(float x) {
  return __expf(x * 0.6931471805599453f);
}
#endif

__global__ __launch_bounds__(512) void lstm_persist(
    const float* __restrict__ data, const float* __restrict__ h0,
    const float* __restrict__ c0, const float* __restrict__ W_ih,
    const float* __restrict__ W_hh, const float* __restrict__ b_ih,
    const float* __restrict__ b_hh, const float* __restrict__ W_out,
    const float* __restrict__ b_out, float* __restrict__ out, int T) {
  __shared__ __align__(16) float xs[TMAX];
  __shared__ __align__(16) _Float16 hrep[2][4 * REPH];

  const int b = blockIdx.x;
  const int tid = threadIdx.x;
  const int q = tid & 3;
  const int e = tid >> 2;

  // Stage input row (coalesced float4).
  {
    const float4* src = (const float4*)(data + (size_t)b * T);
    float4* dst = (float4*)xs;
    for (int i = tid; i < T / 4; i += 512) dst[i] = src[i];
  }

  // Gate scales (folded into weights/bias): pre' = Mk(gate) * preactivation.
  // sigmoid(p) = rcp(1+2^(-p*L2E)); tanh(p) = 1-2*rcp(1+2^(p*2*L2E)).
  constexpr float L2E = 1.44269504088896f;

  // Weights: 4 gate rows x 32 k = 64 packed f16 pairs, pre-scaled by Mk(r).
  v2h w[4][16];
#pragma unroll
  for (int r = 0; r < 4; ++r) {
    const float Mr = (r == 2) ? 2.0f * L2E : -L2E;
    const float* wr = W_hh + (size_t)(e + 128 * r) * Hdim + 32 * q;
#pragma unroll
    for (int j = 0; j < 8; ++j) {
      float4 v = ((const float4*)wr)[j];
      w[r][2 * j + 0] = v2h{(_Float16)(Mr * v.x), (_Float16)(Mr * v.y)};
      w[r][2 * j + 1] = v2h{(_Float16)(Mr * v.z), (_Float16)(Mr * v.w)};
    }
  }

  // Lane-constant activation params for MY gate (q: 0=i,1=f,2=g,3=o).
  const int row = e + 128 * q;
  const float MkL = (q == 2) ? 2.0f * L2E : -L2E;
  const float wihL = MkL * W_ih[row];
  const float bsL = MkL * (b_ih[row] + b_hh[row]);
  const float As = (q == 2) ? -2.0f : 1.0f;
  const float Bs = (q == 2) ? 1.0f : 0.0f;
  const bool qb0 = (q & 1) != 0;
  const bool qb1 = (q & 2) != 0;

  float c = c0[(size_t)b * Hdim + e];
  if (q == 0) {
    const _Float16 hh = (_Float16)h0[(size_t)b * Hdim + e];
    hrep[0][0 * REPH + e] = hh;
    hrep[0][1 * REPH + e] = hh;
    hrep[0][2 * REPH + e] = hh;
    hrep[0][3 * REPH + e] = hh;
  }
  __syncthreads();

  for (int t0 = 0; t0 < T; t0 += 4) {
    const float4 xv = *(const float4*)&xs[t0];  // broadcast, off critical path
    const float xts[4] = {xv.x, xv.y, xv.z, xv.w};
#pragma unroll
    for (int u = 0; u < 4; ++u) {
      const int t = t0 + u;
      // My 32-half chunk of h (4x ds_read_b128, conflict-free stagger).
      const v2h* hp = (const v2h*)(&hrep[t & 1][q * REPH + 32 * q]);
      v2h h2[16];
#pragma unroll
      for (int j = 0; j < 16; ++j) h2[j] = hp[j];

      float a0 = 0.f, a1 = 0.f, a2 = 0.f, a3 = 0.f;
#pragma unroll
      for (int j = 0; j < 16; ++j) {
        a0 = __builtin_amdgcn_fdot2(w[0][j], h2[j], a0, false);
        a1 = __builtin_amdgcn_fdot2(w[1][j], h2[j], a1, false);
        a2 = __builtin_amdgcn_fdot2(w[2][j], h2[j], a2, false);
        a3 = __builtin_amdgcn_fdot2(w[3][j], h2[j], a3, false);
      }

      // 2-stage DPP reduce-scatter: lane q ends with gate q's full sum
      // (already Mk-scaled via the weights).
      float x01 = qb0 ? a1 : a0;
      float y01 = qb0 ? a0 : a1;
      x01 += dppf<0xB1>(y01);
      float x23 = qb0 ? a3 : a2;
      float y23 = qb0 ? a2 : a3;
      x23 += dppf<0xB1>(y23);
      float z = qb1 ? x23 : x01;
      float zz = qb1 ? x01 : x23;
      z += dppf<0x4E>(zz);

      // Activation for my own gate (pre already scaled by Mk).
      const float pre = fmaf(xts[u], wihL, bsL) + z;
      const float y =
          fmaf(As, __builtin_amdgcn_rcpf(1.0f + exp2_fast(pre)), Bs);

      // Quad broadcast: gather i,f,g,o into every lane.
      const float yi = dppf<0x00>(y);
      const float yf = dppf<0x55>(y);
      const float yg = dppf<0xAA>(y);
      const float yo = dppf<0xFF>(y);

      c = fmaf(yf, c, yi * yg);
      const float th = fmaf(
          -2.0f, __builtin_amdgcn_rcpf(1.0f + exp2_fast(c * (2.0f * L2E))),
          1.0f);
      const float h = yo * th;

      hrep[(t + 1) & 1][q * REPH + e] = (_Float16)h;
      __syncthreads();
    }
  }

  // Final linear: out[b] = h_T . W_out + b_out (wave 0, replica 0).
  if (tid < 64) {
    const _Float16* hf = &hrep[T & 1][0];
    float sum =
        (float)hf[tid] * W_out[tid] + (float)hf[tid + 64] * W_out[tid + 64];
#pragma unroll
    for (int off = 32; off > 0; off >>= 1) sum += __shfl_down(sum, off, 64);
    if (tid == 0) out[b] = sum + b_out[0];
  }
}

extern "C" void kernel_launch(void* const* d_in, const int* in_sizes, int n_in,
                              void* d_out, int out_size, void* d_ws,
                              size_t ws_size, hipStream_t stream) {
  const float* data = (const float*)d_in[0];
  const float* h0 = (const float*)d_in[1];
  const float* c0 = (const float*)d_in[2];
  const float* W_ih = (const float*)d_in[3];
  const float* W_hh = (const float*)d_in[4];
  const float* b_ih = (const float*)d_in[5];
  const float* b_hh = (const float*)d_in[6];
  const float* W_out = (const float*)d_in[7];
  const float* b_out = (const float*)d_in[8];
  float* out = (float*)d_out;

  const int B = in_sizes[1] / Hdim;  // 64
  const int T = in_sizes[0] / B;     // 4096

  lstm_persist<<<B, 512, 0, stream>>>(data, h0, c0, W_ih, W_hh, b_ih, b_hh,
                                      W_out, b_out, out, T);
}